// Round 1
// 558.420 us; speedup vs baseline: 1.0775x; 1.0775x over previous
//
#include <hip/hip_runtime.h>
#include <hip/hip_bf16.h>
#include <math.h>

#define T_TOK 8192
#define D_DIM 2048
#define H_DIM 2048
#define E_NUM 8
#define CAP   2048

typedef __attribute__((ext_vector_type(4))) float f32x4;
typedef __attribute__((ext_vector_type(8))) __bf16 bf16x8;

__device__ __forceinline__ unsigned short f2bf(float f) {
  unsigned int u = __float_as_uint(f);
  return (unsigned short)((u + 0x7FFFu + ((u >> 16) & 1u)) >> 16);
}

__device__ __forceinline__ void async_load16(const void* g, void* l) {
  __builtin_amdgcn_global_load_lds(
      (const __attribute__((address_space(1))) void*)g,
      (__attribute__((address_space(3))) void*)l, 16, 0, 0);
}

// ---- fused prep: w1cast (blocks 0..8191) + gate (8192..10239) +
//      w2sum (10240..14335) + b2sum (14336..14337) + init (14338) ----
#define PREP_W1_BLOCKS 8192
#define PREP_GATE_BLOCKS 2048
#define PREP_W2_BLOCKS 4096
#define PREP_TOTAL (PREP_W1_BLOCKS + PREP_GATE_BLOCKS + PREP_W2_BLOCKS + 3)

__global__ __launch_bounds__(256) void prep_kernel(
    const float* __restrict__ x, const float* __restrict__ wg,
    const float* __restrict__ w1, const float* __restrict__ w2,
    const float* __restrict__ b2,
    unsigned short* __restrict__ xbf, int* __restrict__ topidx,
    float* __restrict__ gates, unsigned short* __restrict__ w1t,
    float* __restrict__ w2s, float* __restrict__ b2sum,
    int* __restrict__ slot_token, float* __restrict__ s_out)
{
  __shared__ unsigned short tile[64][68];
  int b = blockIdx.x;
  int tid = threadIdx.x;

  if (b < PREP_W1_BLOCKS) {
    // ---- W1 [E][D][H] fp32 -> W1T [E][H][D] bf16, 64x64 LDS transpose ----
    int e = b >> 10;
    int rem = b & 1023;
    int dt = rem >> 5, ht = rem & 31;
    const float* ibase = w1 + ((size_t)e * D_DIM + dt * 64) * H_DIM + ht * 64;
    int c4 = tid & 15, r0 = tid >> 4;
#pragma unroll
    for (int p = 0; p < 4; ++p) {
      int r = r0 + p * 16;
      float4 v = *(const float4*)(ibase + (size_t)r * H_DIM + c4 * 4);
      tile[r][c4 * 4 + 0] = f2bf(v.x);
      tile[r][c4 * 4 + 1] = f2bf(v.y);
      tile[r][c4 * 4 + 2] = f2bf(v.z);
      tile[r][c4 * 4 + 3] = f2bf(v.w);
    }
    __syncthreads();
    unsigned short* obase = w1t + ((size_t)e * H_DIM + ht * 64) * D_DIM + dt * 64;
    int dq = tid & 7, h0 = tid >> 3;
#pragma unroll
    for (int p = 0; p < 2; ++p) {
      int hh = h0 + p * 32;
      unsigned int pk[4];
#pragma unroll
      for (int u = 0; u < 4; ++u) {
        unsigned int lo = tile[dq * 8 + u * 2][hh];
        unsigned int hi = tile[dq * 8 + u * 2 + 1][hh];
        pk[u] = lo | (hi << 16);
      }
      uint4 ov = make_uint4(pk[0], pk[1], pk[2], pk[3]);
      *(uint4*)(obase + (size_t)hh * D_DIM + dq * 8) = ov;
    }
  } else if (b < PREP_W1_BLOCKS + PREP_GATE_BLOCKS) {
    // ---- gating (fp32 logits, top-2, softmax gates) + x -> bf16 cast ----
    int bx = b - PREP_W1_BLOCKS;
    int w = tid >> 6, lane = tid & 63;
    int t = bx * 4 + w;
    const float4* xr = (const float4*)(x + (size_t)t * D_DIM);
    ushort4* xo = (ushort4*)(xbf + (size_t)t * D_DIM);
    float acc[8];
#pragma unroll
    for (int e = 0; e < 8; ++e) acc[e] = 0.f;
#pragma unroll
    for (int it = 0; it < 8; ++it) {
      int i4 = it * 64 + lane;
      float4 v = xr[i4];
      int d = i4 * 4;
      float xv[4] = {v.x, v.y, v.z, v.w};
#pragma unroll
      for (int u = 0; u < 4; ++u) {
        const float4* wr = (const float4*)(wg + (size_t)(d + u) * 8);
        float4 w01 = wr[0], w23 = wr[1];
        acc[0] += xv[u] * w01.x; acc[1] += xv[u] * w01.y;
        acc[2] += xv[u] * w01.z; acc[3] += xv[u] * w01.w;
        acc[4] += xv[u] * w23.x; acc[5] += xv[u] * w23.y;
        acc[6] += xv[u] * w23.z; acc[7] += xv[u] * w23.w;
      }
      ushort4 o;
      o.x = f2bf(v.x); o.y = f2bf(v.y); o.z = f2bf(v.z); o.w = f2bf(v.w);
      xo[i4] = o;
    }
#pragma unroll
    for (int off = 1; off < 64; off <<= 1) {
#pragma unroll
      for (int e = 0; e < 8; ++e) acc[e] += __shfl_xor(acc[e], off);
    }
    if (lane == 0) {
      int e1 = 0; float l1 = acc[0];
      for (int e = 1; e < 8; ++e) if (acc[e] > l1) { l1 = acc[e]; e1 = e; }
      int e2 = -1; float l2 = -1e30f;
      for (int e = 0; e < 8; ++e) { if (e == e1) continue; if (acc[e] > l2) { l2 = acc[e]; e2 = e; } }
      float tt = expf(l2 - l1);          // <= 1
      float g1 = 1.f / (1.f + tt);
      float g2 = tt / (1.f + tt);
      topidx[t * 2] = e1; topidx[t * 2 + 1] = e2;
      gates[t * 2] = g1;  gates[t * 2 + 1] = g2;
    }
  } else if (b < PREP_W1_BLOCKS + PREP_GATE_BLOCKS + PREP_W2_BLOCKS) {
    // ---- w2sum[e,h] = sum_d W2[e,h,d] ----
    int bx = b - (PREP_W1_BLOCKS + PREP_GATE_BLOCKS);
    int wid = tid >> 6, lane = tid & 63;
    int row = bx * 4 + wid;  // E*H rows
    const float4* r4 = (const float4*)(w2 + (size_t)row * D_DIM);
    float p = 0.f;
#pragma unroll
    for (int i = 0; i < 8; ++i) { float4 v = r4[i * 64 + lane]; p += v.x + v.y + v.z + v.w; }
#pragma unroll
    for (int off = 1; off < 64; off <<= 1) p += __shfl_xor(p, off);
    if (lane == 0) w2s[row] = p;
  } else if (b < PREP_W1_BLOCKS + PREP_GATE_BLOCKS + PREP_W2_BLOCKS + 2) {
    // ---- b2sum[e] = sum_d b2[e,d] ----
    int local = b - (PREP_W1_BLOCKS + PREP_GATE_BLOCKS + PREP_W2_BLOCKS);
    int w = tid >> 6, lane = tid & 63;
    int e = local * 4 + w;
    float p = 0.f;
    for (int i = lane; i < D_DIM; i += 64) p += b2[e * D_DIM + i];
#pragma unroll
    for (int off = 1; off < 64; off <<= 1) p += __shfl_xor(p, off);
    if (lane == 0) b2sum[e] = p;
  } else {
    // ---- init: s_out = 0, slot_token = T_TOK (zero-row), xbf pad row = 0 ----
    for (int i = tid; i < E_NUM * CAP; i += 256) { s_out[i] = 0.f; slot_token[i] = T_TOK; }
    for (int i = tid; i < D_DIM; i += 256) xbf[(size_t)T_TOK * D_DIM + i] = 0;
  }
}

// ------- GShard dispatch scan (single block, deterministic) -------
__global__ __launch_bounds__(1024) void scan_kernel(
    const int* __restrict__ topidx, int* __restrict__ slot_token,
    int* __restrict__ tok_slot, int* __restrict__ kept_count)
{
  __shared__ int cnts[1024 * 8];
  __shared__ int tot0[8];
  int tid = threadIdx.x;
  int w = tid >> 6, lane = tid & 63;

  int base_t = tid * 8;
  int lc[8]; int myi[8];
  // ---------- j = 0 ----------
#pragma unroll
  for (int e = 0; e < 8; ++e) lc[e] = 0;
#pragma unroll
  for (int u = 0; u < 8; ++u) { int ex = topidx[(base_t + u) * 2]; myi[u] = ex; lc[ex]++; }
#pragma unroll
  for (int e = 0; e < 8; ++e) cnts[tid * 8 + e] = lc[e];
  __syncthreads();
  if (w < 8) {
    int e = w;
    int vals[16]; int lsum = 0;
#pragma unroll
    for (int m = 0; m < 16; ++m) { vals[m] = cnts[(lane * 16 + m) * 8 + e]; lsum += vals[m]; }
    int inc = lsum;
    for (int off = 1; off < 64; off <<= 1) { int o = __shfl_up(inc, off); if (lane >= off) inc += o; }
    int run = inc - lsum;
#pragma unroll
    for (int m = 0; m < 16; ++m) { int v = vals[m]; cnts[(lane * 16 + m) * 8 + e] = run; run += v; }
    if (lane == 63) tot0[e] = run;
  }
  __syncthreads();
  int baseo[8];
#pragma unroll
  for (int e = 0; e < 8; ++e) baseo[e] = cnts[tid * 8 + e];
#pragma unroll
  for (int u = 0; u < 8; ++u) {
    int ex = myi[u]; int t = base_t + u;
    int pos = baseo[ex]++;
    if (pos < CAP) { tok_slot[t * 2] = ex * CAP + pos; slot_token[ex * CAP + pos] = t; }
    else tok_slot[t * 2] = -1;
  }
  __syncthreads();
  // ---------- j = 1 ----------
#pragma unroll
  for (int e = 0; e < 8; ++e) lc[e] = 0;
#pragma unroll
  for (int u = 0; u < 8; ++u) { int ex = topidx[(base_t + u) * 2 + 1]; myi[u] = ex; lc[ex]++; }
#pragma unroll
  for (int e = 0; e < 8; ++e) cnts[tid * 8 + e] = lc[e];
  __syncthreads();
  if (w < 8) {
    int e = w;
    int vals[16]; int lsum = 0;
#pragma unroll
    for (int m = 0; m < 16; ++m) { vals[m] = cnts[(lane * 16 + m) * 8 + e]; lsum += vals[m]; }
    int inc = lsum;
    for (int off = 1; off < 64; off <<= 1) { int o = __shfl_up(inc, off); if (lane >= off) inc += o; }
    int run = tot0[e] + inc - lsum;
#pragma unroll
    for (int m = 0; m < 16; ++m) { int v = vals[m]; cnts[(lane * 16 + m) * 8 + e] = run; run += v; }
    if (lane == 63) kept_count[e] = min(run, CAP);
  }
  __syncthreads();
#pragma unroll
  for (int e = 0; e < 8; ++e) baseo[e] = cnts[tid * 8 + e];
#pragma unroll
  for (int u = 0; u < 8; ++u) {
    int ex = myi[u]; int t = base_t + u;
    int pos = baseo[ex]++;
    if (pos < CAP) { tok_slot[t * 2 + 1] = ex * CAP + pos; slot_token[ex * CAP + pos] = t; }
    else tok_slot[t * 2 + 1] = -1;
  }
}

// ======================================================================
// 256x256-tile, BK=64, 8-wave (2Mx4N), 8-phase bf16 MFMA GEMM with
// counted-vmcnt pipelining, XOR-swizzled LDS (conflict-free ds_read_b128),
// fused relu + w2sum-dot epilogue.
//
// LDS: 4 A-slots + 4 B-slots of [256 rows][32 k] bf16 (16 KB each) = 128 KB.
// K-tile t (64 wide) = slabs kh0/kh1 in slots d*2 / d*2+1, d = t&1.
// Staging runs 6 half-slabs ahead; one s_waitcnt vmcnt(4) per K-tile
// boundary (vmcnt(0) only entering the last tile). Race-freedom: each
// slot's new staging is issued after a barrier that follows every wave's
// completed (lgkmcnt-drained) reads of that slot's previous occupant.
// Swizzle: 16B chunk cc ^= (row>>1)&3, applied to the pre-swizzled global
// SOURCE (global_load_lds writes LDS linearly) and to the ds_read address.
// ======================================================================
#define FFN_NT 32   // K tiles of 64 over D_DIM=2048

__global__ __launch_bounds__(512, 2) void ffn_kernel(
    const unsigned short* __restrict__ xbf,    // [(T+1)][D] bf16
    const unsigned short* __restrict__ w1t,    // [E][H][D] bf16
    const float* __restrict__ w2s,             // [E][H]
    const float* __restrict__ b1,              // [E][H]
    const int* __restrict__ slot_token,        // [E][CAP]
    const int* __restrict__ kept_count,        // [E]
    float* __restrict__ s_out)                 // [E][CAP]
{
  int bid = blockIdx.x;
  int swz = (bid & 7) * 64 + (bid >> 3);   // bijective XCD swizzle (512 % 8 == 0)
  int e = swz >> 6;
  int rem = swz & 63;
  int mt = rem >> 3, nt = rem & 7;
  if (mt * 256 >= kept_count[e]) return;

  __shared__ unsigned short Asl[4][256 * 32];   // 64 KB
  __shared__ unsigned short Bsl[4][256 * 32];   // 64 KB

  int tid = threadIdx.x;
  int w = tid >> 6, lane = tid & 63;
  int wr = w >> 2, wc = w & 3;                  // 2M x 4N waves
  int l15 = lane & 15, q = lane >> 4;

  // ---- staging source setup (pre-swizzled per-lane global addresses) ----
  int r0s = tid >> 2;                           // rows 0..127 (chunk = 16B)
  int ccs = tid & 3;                            // chunk within 64B row
  int sw0 = (ccs ^ ((r0s >> 1) & 3)) * 8;       // swizzled element offset
  int r1s = r0s + 128;
  int sw1 = (ccs ^ ((r1s >> 1) & 3)) * 8;
  int tokl = slot_token[e * CAP + mt * 256 + r0s];
  int tokh = slot_token[e * CAP + mt * 256 + r1s];
  const unsigned short* gA0 = xbf + (size_t)tokl * D_DIM + sw0;
  const unsigned short* gA1 = xbf + (size_t)tokh * D_DIM + sw1;
  const unsigned short* gB0 = w1t + ((size_t)e * H_DIM + nt * 256 + r0s) * D_DIM + sw0;
  const unsigned short* gB1 = w1t + ((size_t)e * H_DIM + nt * 256 + r1s) * D_DIM + sw1;

  // ---- fragment ds_read addressing (same swizzle) ----
  int rowAa = wr * 128 + l15;
  int rowBb = wc * 64 + l15;
  int offA = rowAa * 32 + (q ^ ((rowAa >> 1) & 3)) * 8;
  int offB = rowBb * 32 + (q ^ ((rowBb >> 1) & 3)) * 8;

  // one STAGE = one half-slab = 2 loads/thread (vmcnt counts 2 per slab)
#define STAGE(SLOT_PTR, G0, G1, KOFS)                                    \
  do {                                                                   \
    async_load16((G0) + (KOFS), (SLOT_PTR) + w * 512);                   \
    async_load16((G1) + (KOFS), (SLOT_PTR) + 4096 + w * 512);            \
  } while (0)

  f32x4 acc[8][4];
#pragma unroll
  for (int i = 0; i < 8; ++i)
#pragma unroll
    for (int j = 0; j < 4; ++j) acc[i][j] = (f32x4)(0.f);

  // ---- prologue: stage (0,A0)(0,B0)(0,A1)(0,B1)(1,A0)(1,B0) ----
  STAGE(&Asl[0][0], gA0, gA1, 0);
  STAGE(&Bsl[0][0], gB0, gB1, 0);
  STAGE(&Asl[1][0], gA0, gA1, 32);
  STAGE(&Bsl[1][0], gB0, gB1, 32);
  STAGE(&Asl[2][0], gA0, gA1, 64);
  STAGE(&Bsl[2][0], gB0, gB1, 64);
  asm volatile("s_waitcnt vmcnt(4)" ::: "memory");   // tile 0 landed, 2 slabs in flight
  __builtin_amdgcn_s_barrier();
  __builtin_amdgcn_sched_barrier(0);

  for (int t = 0; t < FFN_NT; ++t) {
    int d = t & 1;
    const unsigned short* Ak0 = &Asl[d * 2][0];
    const unsigned short* Ak1 = &Asl[d * 2 + 1][0];
    const unsigned short* Bk0 = &Bsl[d * 2][0];
    const unsigned short* Bk1 = &Bsl[d * 2 + 1][0];

    bf16x8 aF[4], bK0[4], bK1[4];

    // ===== phase 0: read A(kh0,m0-3)+B(kh0); stage (t+1,A1); mfma m0-3 kh0 =====
#pragma unroll
    for (int mf = 0; mf < 4; ++mf) aF[mf] = *(const bf16x8*)(Ak0 + offA + mf * 512);
#pragma unroll
    for (int nf = 0; nf < 4; ++nf) bK0[nf] = *(const bf16x8*)(Bk0 + offB + nf * 512);
    if (t < FFN_NT - 1) STAGE(&Asl[(d ^ 1) * 2 + 1][0], gA0, gA1, (t + 1) * 64 + 32);
    __builtin_amdgcn_s_barrier();
    __builtin_amdgcn_sched_barrier(0);
    __builtin_amdgcn_s_setprio(1);
#pragma unroll
    for (int mf = 0; mf < 4; ++mf)
#pragma unroll
      for (int nf = 0; nf < 4; ++nf)
        acc[mf][nf] = __builtin_amdgcn_mfma_f32_16x16x32_bf16(aF[mf], bK0[nf], acc[mf][nf], 0, 0, 0);
    __builtin_amdgcn_s_setprio(0);
    __builtin_amdgcn_s_barrier();
    __builtin_amdgcn_sched_barrier(0);

    // ===== phase 1: read A(kh0,m4-7)+B(kh1); stage (t+1,B1); mfma m4-7 kh0 =====
#pragma unroll
    for (int mf = 0; mf < 4; ++mf) aF[mf] = *(const bf16x8*)(Ak0 + offA + (mf + 4) * 512);
#pragma unroll
    for (int nf = 0; nf < 4; ++nf) bK1[nf] = *(const bf16x8*)(Bk1 + offB + nf * 512);
    if (t < FFN_NT - 1) STAGE(&Bsl[(d ^ 1) * 2 + 1][0], gB0, gB1, (t + 1) * 64 + 32);
    __builtin_amdgcn_s_barrier();
    __builtin_amdgcn_sched_barrier(0);
    __builtin_amdgcn_s_setprio(1);
#pragma unroll
    for (int mf = 0; mf < 4; ++mf)
#pragma unroll
      for (int nf = 0; nf < 4; ++nf)
        acc[mf + 4][nf] = __builtin_amdgcn_mfma_f32_16x16x32_bf16(aF[mf], bK0[nf], acc[mf + 4][nf], 0, 0, 0);
    __builtin_amdgcn_s_setprio(0);
    __builtin_amdgcn_s_barrier();
    __builtin_amdgcn_sched_barrier(0);

    // ===== phase 2: read A(kh1,m0-3); stage (t+2,A0); mfma m0-3 kh1 =====
#pragma unroll
    for (int mf = 0; mf < 4; ++mf) aF[mf] = *(const bf16x8*)(Ak1 + offA + mf * 512);
    if (t < FFN_NT - 2) STAGE(&Asl[d * 2][0], gA0, gA1, (t + 2) * 64);
    __builtin_amdgcn_s_barrier();
    __builtin_amdgcn_sched_barrier(0);
    __builtin_amdgcn_s_setprio(1);
#pragma unroll
    for (int mf = 0; mf < 4; ++mf)
#pragma unroll
      for (int nf = 0; nf < 4; ++nf)
        acc[mf][nf] = __builtin_amdgcn_mfma_f32_16x16x32_bf16(aF[mf], bK1[nf], acc[mf][nf], 0, 0, 0);
    __builtin_amdgcn_s_setprio(0);
    __builtin_amdgcn_s_barrier();
    __builtin_amdgcn_sched_barrier(0);

    // ===== phase 3: read A(kh1,m4-7); stage (t+2,B0); mfma m4-7 kh1; boundary =====
#pragma unroll
    for (int mf = 0; mf < 4; ++mf) aF[mf] = *(const bf16x8*)(Ak1 + offA + (mf + 4) * 512);
    if (t < FFN_NT - 2) STAGE(&Bsl[d * 2][0], gB0, gB1, (t + 2) * 64);
    __builtin_amdgcn_s_barrier();
    __builtin_amdgcn_sched_barrier(0);
    __builtin_amdgcn_s_setprio(1);
#pragma unroll
    for (int mf = 0; mf < 4; ++mf)
#pragma unroll
      for (int nf = 0; nf < 4; ++nf)
        acc[mf + 4][nf] = __builtin_amdgcn_mfma_f32_16x16x32_bf16(aF[mf], bK1[nf], acc[mf + 4][nf], 0, 0, 0);
    __builtin_amdgcn_s_setprio(0);
    if (t < FFN_NT - 2) {
      // tile t+1 fully landed; 2 slabs (t+2,A0)(t+2,B0) stay in flight
      asm volatile("s_waitcnt vmcnt(4)" ::: "memory");
    } else {
      // no further prefetch: drain before the last tile
      asm volatile("s_waitcnt vmcnt(0)" ::: "memory");
    }
    __builtin_amdgcn_s_barrier();
    __builtin_amdgcn_sched_barrier(0);
  }
#undef STAGE

  // ---- epilogue: s[m] = sum_n relu(z + b1[n]) * w2sum[n] ----
  float sp[8][4];
#pragma unroll
  for (int mf = 0; mf < 8; ++mf)
#pragma unroll
    for (int r = 0; r < 4; ++r) sp[mf][r] = 0.f;
#pragma unroll
  for (int nf = 0; nf < 4; ++nf) {
    int n = nt * 256 + wc * 64 + nf * 16 + l15;
    float w2v = w2s[e * H_DIM + n];
    float b1v = b1[e * H_DIM + n];
#pragma unroll
    for (int mf = 0; mf < 8; ++mf)
#pragma unroll
      for (int r = 0; r < 4; ++r) {
        float z = acc[mf][nf][r] + b1v;
        sp[mf][r] += fmaxf(z, 0.f) * w2v;
      }
  }
#pragma unroll
  for (int off = 1; off < 16; off <<= 1)
#pragma unroll
    for (int mf = 0; mf < 8; ++mf)
#pragma unroll
      for (int r = 0; r < 4; ++r) sp[mf][r] += __shfl_xor(sp[mf][r], off);
  if (l15 == 0) {
    int mbase = e * CAP + mt * 256 + wr * 128 + q * 4;
#pragma unroll
    for (int mf = 0; mf < 8; ++mf)
#pragma unroll
      for (int r = 0; r < 4; ++r)
        atomicAdd(&s_out[mbase + mf * 16 + r], sp[mf][r]);
  }
}

// ---------------- combine + per-batch log_softmax ----------------
__global__ __launch_bounds__(1024) void combine_kernel(
    const float* __restrict__ s_in, const int* __restrict__ tok_slot,
    const float* __restrict__ gates, const float* __restrict__ b2sum,
    float* __restrict__ out)
{
  __shared__ float red[1024];
  int b = blockIdx.x, tid = threadIdx.x;
  float y[2];
  float mx = -1e30f;
#pragma unroll
  for (int i = 0; i < 2; ++i) {
    int t = b * 2048 + i * 1024 + tid;
    float accv = 0.f;
#pragma unroll
    for (int j = 0; j < 2; ++j) {
      int sl = tok_slot[t * 2 + j];
      if (sl >= 0) accv += gates[t * 2 + j] * (s_in[sl] + b2sum[sl >> 11]);
    }
    y[i] = accv;
    mx = fmaxf(mx, accv);
  }
  red[tid] = mx; __syncthreads();
  for (int st = 512; st > 0; st >>= 1) {
    if (tid < st) red[tid] = fmaxf(red[tid], red[tid + st]);
    __syncthreads();
  }
  mx = red[0]; __syncthreads();
  float se = 0.f;
#pragma unroll
  for (int i = 0; i < 2; ++i) se += expf(y[i] - mx);
  red[tid] = se; __syncthreads();
  for (int st = 512; st > 0; st >>= 1) {
    if (tid < st) red[tid] += red[tid + st];
    __syncthreads();
  }
  float logZ = mx + logf(red[0]);
#pragma unroll
  for (int i = 0; i < 2; ++i) out[b * 2048 + i * 1024 + tid] = y[i] - logZ;
}

extern "C" void kernel_launch(void* const* d_in, const int* in_sizes, int n_in,
                              void* d_out, int out_size, void* d_ws, size_t ws_size,
                              hipStream_t stream) {
  const float* x  = (const float*)d_in[0];
  const float* wg = (const float*)d_in[1];
  const float* w1 = (const float*)d_in[2];
  const float* b1 = (const float*)d_in[3];
  const float* w2 = (const float*)d_in[4];
  const float* b2 = (const float*)d_in[5];
  float* out = (float*)d_out;

  char* ws = (char*)d_ws;
  size_t off = 0;
  auto alloc = [&](size_t bytes) -> void* {
    void* p = ws + off; off += (bytes + 255) & ~(size_t)255; return p;
  };
  unsigned short* xbf   = (unsigned short*)alloc((size_t)(T_TOK + 1) * D_DIM * 2);
  unsigned short* w1t   = (unsigned short*)alloc((size_t)E_NUM * D_DIM * H_DIM * 2);
  float* w2s            = (float*)alloc((size_t)E_NUM * H_DIM * 4);
  float* gates          = (float*)alloc((size_t)T_TOK * 2 * 4);
  int*   topidx         = (int*)alloc((size_t)T_TOK * 2 * 4);
  int*   tok_slot       = (int*)alloc((size_t)T_TOK * 2 * 4);
  int*   slot_token     = (int*)alloc((size_t)E_NUM * CAP * 4);
  float* s_buf          = (float*)alloc((size_t)E_NUM * CAP * 4);
  float* b2s            = (float*)alloc(256);
  int*   kept           = (int*)alloc(256);

  prep_kernel<<<PREP_TOTAL, 256, 0, stream>>>(x, wg, w1, w2, b2, xbf, topidx,
                                              gates, w1t, w2s, b2s, slot_token, s_buf);
  scan_kernel<<<1, 1024, 0, stream>>>(topidx, slot_token, tok_slot, kept);
  ffn_kernel<<<E_NUM * 8 * 8, 512, 0, stream>>>(xbf, w1t, w2s, b1, slot_token, kept, s_buf);
  combine_kernel<<<4, 1024, 0, stream>>>(s_buf, tok_slot, gates, b2s, out);
}